// Round 8
// baseline (12197.334 us; speedup 1.0000x reference)
//
#include <hip/hip_runtime.h>
#include <math.h>

#define BB 512
#define HH 512
#define FF 72
#define NCC 10
#define EE 64
#define TTRAJ 120
#define TOUT 120
#define INWW 713
#define GG 2048
#define WSZE ((size_t)GG*1024)    // elements per converted weight matrix
#define BH  ((size_t)BB*HH)       // elements per activation buffer

typedef _Float16 f16x8 __attribute__((ext_vector_type(8)));
typedef float f32x4 __attribute__((ext_vector_type(4)));

__device__ __forceinline__ float sigmoidf_(float x){ return 1.0f/(1.0f+__expf(-x)); }

// Plain pipelined 16B load (L1-cacheable). Cross-CU freshness is provided by
// the per-barrier fence(acquire, agent) -> buffer_inv (L1 invalidate), NOT by
// per-load volatile (round 7 showed volatile serializes: s_waitcnt after each
// load = ~13us per layer_step).
__device__ __forceinline__ f16x8 ldA(const _Float16* p){
    return *(const f16x8*)p;
}

// Build fp16 Wcat[g*512+j][0:512]=Wih, [512:1024]=Whh
__global__ void conv_wcat_kernel(const float* __restrict__ ih,
                                 const float* __restrict__ hh,
                                 _Float16* __restrict__ dst)
{
    int idx = blockIdx.x*256 + threadIdx.x;   // 2048*256 quads
    int j  = idx >> 8;
    int k4 = (idx & 255) * 4;
    const float* src = (k4 < 512) ? (ih + (size_t)j*512 + k4)
                                  : (hh + (size_t)j*512 + (k4-512));
    float4 v = *(const float4*)src;
    _Float16* d = dst + (size_t)j*1024 + k4;
    d[0] = (_Float16)v.x; d[1] = (_Float16)v.y;
    d[2] = (_Float16)v.z; d[3] = (_Float16)v.w;
}

// cond_out[b*H+j] = emb_b[j] + sum_i (label outer cemb)[b,i]*emb_W[j][72+i]
__global__ void cond_kernel(const float* __restrict__ label,
                            const float* __restrict__ cemb,
                            const float* __restrict__ embW,
                            const float* __restrict__ embB,
                            float* __restrict__ cond_out)
{
    __shared__ float sl[NCC];
    __shared__ float se[EE];
    __shared__ float sc[NCC*EE];
    int b = blockIdx.x;
    int tid = threadIdx.x;
    if (tid < NCC) sl[tid] = label[b*NCC + tid];
    else if (tid >= 32 && tid < 32+EE) se[tid-32] = cemb[b*EE + (tid-32)];
    __syncthreads();
    for (int i = tid; i < NCC*EE; i += 256) sc[i] = sl[i>>6]*se[i&63];
    __syncthreads();
    for (int j = tid; j < HH; j += 256){
        const float* w = embW + (size_t)j*INWW + FF;
        float acc = embB[j];
        #pragma unroll 8
        for (int i = 0; i < NCC*EE; ++i) acc += sc[i]*w[i];
        cond_out[b*HH + j] = acc;
    }
}

// Mf[j][k] = sum_f embW[j][f]*outW[f][k]   (fp16 out)
__global__ void mf_kernel(const float* __restrict__ embW,
                          const float* __restrict__ outW,
                          _Float16* __restrict__ Mf)
{
    int idx = blockIdx.x*256 + threadIdx.x;   // 512*512
    int j = idx >> 9, k = idx & 511;
    const float* ew = embW + (size_t)j*INWW;
    float acc = 0.f;
    #pragma unroll 8
    for (int f = 0; f < FF; ++f) acc += ew[f] * outW[f*512 + k];
    Mf[idx] = (_Float16)acc;
}

// biasC[4][2048], w712[512], constj[512], outWf[80][512] (fp16, zero-padded)
__global__ void prep_kernel(const float* __restrict__ encbih, const float* __restrict__ encbhh,
                            const float* __restrict__ decbih, const float* __restrict__ decbhh,
                            const float* __restrict__ embW, const float* __restrict__ outW,
                            const float* __restrict__ outB,
                            float* __restrict__ biasC, float* __restrict__ w712,
                            float* __restrict__ constj, _Float16* __restrict__ outWf)
{
    int i = blockIdx.x*256 + threadIdx.x;
    if (i < 8192){
        int l = i >> 11, g = i & 2047;
        biasC[i] = (l < 2) ? encbih[l*GG+g] + encbhh[l*GG+g]
                           : decbih[(l-2)*GG+g] + decbhh[(l-2)*GG+g];
    } else if (i < 8704){
        int j = i - 8192;
        w712[j] = embW[(size_t)j*INWW + (INWW-1)];
    } else if (i < 9216){
        int j = i - 8704;
        float acc = 0.f;
        #pragma unroll 8
        for (int f = 0; f < FF; ++f) acc += embW[(size_t)j*INWW + f] * outB[f];
        constj[j] = acc;
    } else if (i < 9216 + 80*512){
        int ii = i - 9216;
        int f = ii >> 9, k = ii & 511;
        outWf[ii] = (f < FF) ? (_Float16)outW[f*512 + k] : (_Float16)0.f;
    }
}

// ---------------- persistent kernel (normal launch + flag group barriers) ----
// 256 blocks x 256 threads, 1 block/CU. rt = bid&7 (XCD-local group of 32 blocks),
// jt = bid>>3. Block owns rows rt*64..+63, h-cols jt*16..+15. Wave w = gate w.
__global__ __launch_bounds__(256, 1)
void persistent_kernel(const _Float16* __restrict__ wcat, const float* __restrict__ biasC,
                       const float* __restrict__ traj, const float* __restrict__ encW,
                       const float* __restrict__ encB, const float* __restrict__ prelu_a,
                       _Float16* __restrict__ xping, _Float16* __restrict__ h0p,
                       _Float16* __restrict__ h1p, _Float16* __restrict__ xdec,
                       const float* __restrict__ cond, const _Float16* __restrict__ Mf,
                       const float* __restrict__ w712, const float* __restrict__ constj,
                       const _Float16* __restrict__ outWf, const float* __restrict__ outB,
                       float* __restrict__ dout, unsigned* __restrict__ bar)
{
    __shared__ float gx[4][64][17];
    __shared__ float cst[2][64][17];

    const int tid = threadIdx.x;
    const int w    = tid >> 6;       // gate / row-subtile
    const int lane = tid & 63;
    const int m    = lane & 15;
    const int q    = lane >> 4;
    const int bid  = blockIdx.x;
    const int rt   = bid & 7;        // group id (XCD-local under %8 round-robin)
    const int jt   = bid >> 3;       // 0..31
    const int r0   = rt * 64;
    const int j0   = jt * 16;
    const float pa = prelu_a[0];
    unsigned* fl = bar + rt*32*32;   // 32 flags, 128B apart
    unsigned seq = 0;

    // Flag barrier: __syncthreads() drains this block's stores to the XCD L2
    // (s_waitcnt vmcnt(0) before s_barrier), then a plain volatile store of the
    // monotone seq to this block's own flag (no RMW contention, no agent-release
    // -> no buffer_wbl2; round 7 verified WRITE_SIZE 27 MB). Wave 0 polls all 32
    // flags with sc0 loads (don't allocate in L1). After the poll, ONE
    // fence(acquire, agent) -> buffer_inv invalidates L1 so the pipelined,
    // L1-cacheable data loads (ldA) see the producers' fresh L2 lines
    // (round 5 validated this data path end-to-end).
    auto gbar = [&](){
        ++seq;
        __syncthreads();
        if (tid == 0)
            *(volatile unsigned*)(fl + jt*32) = seq;
        if (tid < 64){
            long long t0 = clock64();
            for(;;){
                unsigned v = (tid < 32) ? *(volatile unsigned*)(fl + tid*32) : seq;
                if (__ballot((int)(seq - v) > 0) == 0ULL) break;
                __builtin_amdgcn_s_sleep(1);
                if (clock64() - t0 > 40000000LL) break;   // bail: wrong answer beats hang
            }
        }
        __builtin_amdgcn_fence(__ATOMIC_ACQUIRE, "agent");   // buffer_inv (L1)
        __syncthreads();
    };

    for (int i = tid; i < 2*64*17; i += 256) (&cst[0][0][0])[i] = 0.f;

    f16x8 WB0[32], WB1[32];
    auto load_wb = [&](const _Float16* base0, const _Float16* base1){
        const _Float16* p0 = base0 + ((size_t)(w*512 + j0 + m))*1024 + q*8;
        const _Float16* p1 = base1 + ((size_t)(w*512 + j0 + m))*1024 + q*8;
        #pragma unroll
        for (int kc = 0; kc < 32; ++kc){
            WB0[kc] = *(const f16x8*)(p0 + kc*32);
            WB1[kc] = *(const f16x8*)(p1 + kc*32);
        }
    };

    auto layer_step = [&](const f16x8* WB, float bb, const _Float16* A1, const _Float16* A2,
                          _Float16* dst, int cidx){
        f32x4 acc[4];
        #pragma unroll
        for (int rf = 0; rf < 4; ++rf){ acc[rf][0]=bb; acc[rf][1]=bb; acc[rf][2]=bb; acc[rf][3]=bb; }
        const _Float16* a1 = A1 + ((size_t)(r0 + m))*512 + q*8;
        #pragma unroll
        for (int kc = 0; kc < 16; ++kc){
            #pragma unroll
            for (int rf = 0; rf < 4; ++rf){
                f16x8 av = ldA(a1 + (size_t)rf*16*512 + kc*32);
                acc[rf] = __builtin_amdgcn_mfma_f32_16x16x32_f16(av, WB[kc], acc[rf], 0,0,0);
            }
        }
        const _Float16* a2 = A2 + ((size_t)(r0 + m))*512 + q*8;
        #pragma unroll
        for (int kc = 0; kc < 16; ++kc){
            #pragma unroll
            for (int rf = 0; rf < 4; ++rf){
                f16x8 av = ldA(a2 + (size_t)rf*16*512 + kc*32);
                acc[rf] = __builtin_amdgcn_mfma_f32_16x16x32_f16(av, WB[16+kc], acc[rf], 0,0,0);
            }
        }
        __syncthreads();
        #pragma unroll
        for (int rf = 0; rf < 4; ++rf)
            #pragma unroll
            for (int r = 0; r < 4; ++r)
                gx[w][rf*16 + q*4 + r][m] = acc[rf][r];
        __syncthreads();
        #pragma unroll
        for (int r = 0; r < 4; ++r){
            int row = w*16 + q*4 + r;
            float ig = sigmoidf_(gx[0][row][m]);
            float fg = sigmoidf_(gx[1][row][m]);
            float gv = tanhf(gx[2][row][m]);
            float og = sigmoidf_(gx[3][row][m]);
            float cp = cst[cidx][row][m];
            float cn = fg*cp + ig*gv;
            cst[cidx][row][m] = cn;
            dst[((size_t)(r0 + row))*512 + j0 + m] = (_Float16)(og*tanhf(cn));
        }
    };

    auto gen_x = [&](int t, _Float16* xd){
        #pragma unroll
        for (int e = 0; e < 4; ++e){
            int idx = e*256 + tid;
            int row = r0 + jt*2 + (idx >> 9);
            int col = idx & 511;
            const float* tr = traj + ((size_t)row*TTRAJ + t)*3;
            const float* wv = encW + col*3;
            float v = encB[col] + tr[0]*wv[0] + tr[1]*wv[1] + tr[2]*wv[2];
            xd[(size_t)row*512 + col] = (_Float16)(v >= 0.f ? v : pa*v);
        }
    };

    auto emb_step = [&](int d, const _Float16* h1prev){
        f32x4 acc = {0.f,0.f,0.f,0.f};
        if (d > 0){
            const _Float16* ap = h1prev + ((size_t)(r0 + w*16 + m))*512 + q*8;
            const _Float16* bp = Mf + ((size_t)(j0 + m))*512 + q*8;
            #pragma unroll
            for (int kc = 0; kc < 16; ++kc)
                acc = __builtin_amdgcn_mfma_f32_16x16x32_f16(
                    ldA(ap + kc*32), *(const f16x8*)(bp + kc*32), acc, 0,0,0);
        }
        const int col = j0 + m;
        const float ts = (float)(d+1) * (1.0f/120.0f);
        const float add = ts * w712[col] + ((d > 0) ? constj[col] : 0.f);
        #pragma unroll
        for (int r = 0; r < 4; ++r){
            int row = r0 + w*16 + q*4 + r;
            float v = acc[r] + cond[(size_t)row*512 + col] + add;
            xdec[(size_t)row*512 + col] = (_Float16)(v >= 0.f ? v : pa*v);
        }
    };

    // out tiles stay inside group rows: block jt<20, wave 0: tile (jt/5, jt%5)
    auto out_step = [&](int dprev, const _Float16* h1v){
        if (jt >= 20 || w != 0) return;
        int b0 = r0 + (jt/5)*16;
        int f0 = (jt%5)*16;
        f32x4 acc = {0.f,0.f,0.f,0.f};
        const _Float16* ap = h1v + ((size_t)(b0 + m))*512 + q*8;
        const _Float16* bp = outWf + ((size_t)(f0 + m))*512 + q*8;
        #pragma unroll
        for (int kc = 0; kc < 16; ++kc)
            acc = __builtin_amdgcn_mfma_f32_16x16x32_f16(
                ldA(ap + kc*32), *(const f16x8*)(bp + kc*32), acc, 0,0,0);
        int f = f0 + m;
        if (f < FF){
            float ob = outB[f];
            #pragma unroll
            for (int r = 0; r < 4; ++r){
                int b = b0 + q*4 + r;
                dout[((size_t)b*TOUT + dprev)*FF + f] = acc[r] + ob;
            }
        }
    };

    // ---- load encoder weights into registers ----
    load_wb(wcat + 0*WSZE, wcat + 1*WSZE);
    float bb0 = biasC[0*GG + w*512 + j0 + m];
    float bb1 = biasC[1*GG + w*512 + j0 + m];
    __syncthreads();

    gen_x(0, xping);
    gbar();

    // ---- encoder: segment t pairs L1(t-1) with L0(t): 1 barrier per step ----
    for (int t = 0; t <= 120; ++t){
        int cur = t & 1, prv = cur ^ 1;
        if (t >= 1)
            layer_step(WB1, bb1, h0p + (size_t)prv*BH, h1p + (size_t)cur*BH, h1p + (size_t)prv*BH, 1);
        if (t < 120){
            layer_step(WB0, bb0, xping + (size_t)cur*BH, h0p + (size_t)prv*BH, h0p + (size_t)cur*BH, 0);
            if (t + 1 < 120) gen_x(t + 1, xping + (size_t)prv*BH);
        }
        gbar();
    }

    // ---- decoder: reload registers with decoder weights ----
    load_wb(wcat + 2*WSZE, wcat + 3*WSZE);
    bb0 = biasC[2*GG + w*512 + j0 + m];
    bb1 = biasC[3*GG + w*512 + j0 + m];

    for (int d = 0; d < 120; ++d){
        int t = 120 + d; int cur = t & 1, prv = cur ^ 1;
        emb_step(d, h1p + (size_t)prv*BH);
        if (d > 0) out_step(d - 1, h1p + (size_t)prv*BH);
        gbar();
        layer_step(WB0, bb0, xdec, h0p + (size_t)prv*BH, h0p + (size_t)cur*BH, 0);
        gbar();
        layer_step(WB1, bb1, h0p + (size_t)cur*BH, h1p + (size_t)prv*BH, h1p + (size_t)cur*BH, 1);
        gbar();
    }
    out_step(119, h1p + (size_t)1*BH);
}

extern "C" void kernel_launch(void* const* d_in, const int* in_sizes, int n_in,
                              void* d_out, int out_size, void* d_ws, size_t ws_size,
                              hipStream_t stream)
{
    (void)in_sizes; (void)n_in; (void)out_size; (void)ws_size;
    const float* label   = (const float*)d_in[1];
    const float* cemb    = (const float*)d_in[2];
    const float* traj    = (const float*)d_in[3];
    const float* encW    = (const float*)d_in[4];
    const float* encB    = (const float*)d_in[5];
    const float* prelu_a = (const float*)d_in[6];
    const float* embW    = (const float*)d_in[7];
    const float* embB    = (const float*)d_in[8];
    const float* outW    = (const float*)d_in[9];
    const float* outB    = (const float*)d_in[10];
    const float* encWih  = (const float*)d_in[11];
    const float* encWhh  = (const float*)d_in[12];
    const float* encbih  = (const float*)d_in[13];
    const float* encbhh  = (const float*)d_in[14];
    const float* decWih  = (const float*)d_in[15];
    const float* decWhh  = (const float*)d_in[16];
    const float* decbih  = (const float*)d_in[17];
    const float* decbhh  = (const float*)d_in[18];
    float* out = (float*)d_out;

    char* ws = (char*)d_ws;
    size_t off = 0;
    auto alloc = [&](size_t bytes)->char*{
        char* p = ws + off; off = (off + bytes + 255) & ~(size_t)255; return p;
    };
    _Float16* wcat  = (_Float16*)alloc(4*WSZE*2);
    _Float16* xping = (_Float16*)alloc(2*BH*2);
    _Float16* h0p   = (_Float16*)alloc(2*BH*2);
    _Float16* h1p   = (_Float16*)alloc(2*BH*2);
    _Float16* xdec  = (_Float16*)alloc(BH*2);
    float*    cond  = (float*)   alloc(BH*4);
    _Float16* Mf    = (_Float16*)alloc(512*512*2);
    _Float16* outWf = (_Float16*)alloc(80*512*2);
    float*    biasC = (float*)   alloc(4*GG*4);
    float*    w712  = (float*)   alloc(512*4);
    float*    constj= (float*)   alloc(512*4);
    unsigned* bar   = (unsigned*)alloc(8*32*32*4);   // 8 groups x 32 flags x 128B

    // zero h0p + h1p (contiguous 2MB) and barrier flags
    hipMemsetAsync(h0p, 0, 4*BH*2, stream);
    hipMemsetAsync(bar, 0, 8*32*32*4, stream);

    conv_wcat_kernel<<<2048, 256, 0, stream>>>(encWih,                 encWhh,                 wcat + 0*WSZE);
    conv_wcat_kernel<<<2048, 256, 0, stream>>>(encWih + (size_t)GG*HH, encWhh + (size_t)GG*HH, wcat + 1*WSZE);
    conv_wcat_kernel<<<2048, 256, 0, stream>>>(decWih,                 decWhh,                 wcat + 2*WSZE);
    conv_wcat_kernel<<<2048, 256, 0, stream>>>(decWih + (size_t)GG*HH, decWhh + (size_t)GG*HH, wcat + 3*WSZE);
    cond_kernel<<<BB, 256, 0, stream>>>(label, cemb, embW, embB, cond);
    mf_kernel<<<1024, 256, 0, stream>>>(embW, outW, Mf);
    prep_kernel<<<197, 256, 0, stream>>>(encbih, encbhh, decbih, decbhh, embW, outW, outB,
                                         biasC, w712, constj, outWf);

    persistent_kernel<<<256, 256, 0, stream>>>(
        wcat, biasC, traj, encW, encB, prelu_a, xping, h0p, h1p, xdec,
        cond, Mf, w712, constj, outWf, outB, out, bar);
}

// Round 9
// 9150.953 us; speedup vs baseline: 1.3329x; 1.3329x over previous
//
#include <hip/hip_runtime.h>
#include <math.h>

#define BB 512
#define HH 512
#define FF 72
#define NCC 10
#define EE 64
#define TTRAJ 120
#define TOUT 120
#define INWW 713
#define GG 2048
#define WSZE ((size_t)GG*1024)    // elements per converted weight matrix
#define BH  ((size_t)BB*HH)       // elements per activation buffer

typedef _Float16 f16x8 __attribute__((ext_vector_type(8)));
typedef float f32x4 __attribute__((ext_vector_type(4)));
typedef int i32x4 __attribute__((ext_vector_type(4)));

__device__ __forceinline__ float sigmoidf_(float x){ return 1.0f/(1.0f+__expf(-x)); }

// Pipelined sc0 (L1-bypass) 16B load via raw buffer intrinsic. cpol=1 -> glc,
// which gfx950 encodes as sc0: the load misses L1 and reads the XCD L2 directly
// (where same-XCD producers' dirty activation lines live — validated r5/r7),
// but unlike volatile it is scheduled/batched like a normal load (no per-load
// s_waitcnt serialization, which was round 7's ~13us/layer_step cost).
extern "C" __device__ f32x4 llvm_amdgcn_raw_buffer_load_v4f32(
    i32x4 rsrc, int voffset, int soffset, int cpol) __asm("llvm.amdgcn.raw.buffer.load.v4f32");

__device__ __forceinline__ i32x4 make_srd(const void* p){
    union { const void* p; unsigned long long u; } a; a.p = p;
    i32x4 r;
    r.x = (int)(a.u & 0xFFFFFFFFull);
    r.y = (int)(a.u >> 32);          // stride=0, base hi bits
    r.z = -1;                        // num_records = 0xFFFFFFFF (bounds off)
    r.w = 0x00020000;                // raw dword access
    return r;
}

__device__ __forceinline__ f16x8 ldA(i32x4 srd, int voff){
    f32x4 v = llvm_amdgcn_raw_buffer_load_v4f32(srd, voff, 0, 1);  // sc0
    union { f32x4 f; f16x8 h; } u; u.f = v; return u.h;
}

// Build fp16 Wcat[g*512+j][0:512]=Wih, [512:1024]=Whh
__global__ void conv_wcat_kernel(const float* __restrict__ ih,
                                 const float* __restrict__ hh,
                                 _Float16* __restrict__ dst)
{
    int idx = blockIdx.x*256 + threadIdx.x;   // 2048*256 quads
    int j  = idx >> 8;
    int k4 = (idx & 255) * 4;
    const float* src = (k4 < 512) ? (ih + (size_t)j*512 + k4)
                                  : (hh + (size_t)j*512 + (k4-512));
    float4 v = *(const float4*)src;
    _Float16* d = dst + (size_t)j*1024 + k4;
    d[0] = (_Float16)v.x; d[1] = (_Float16)v.y;
    d[2] = (_Float16)v.z; d[3] = (_Float16)v.w;
}

// cond_out[b*H+j] = emb_b[j] + sum_i (label outer cemb)[b,i]*emb_W[j][72+i]
__global__ void cond_kernel(const float* __restrict__ label,
                            const float* __restrict__ cemb,
                            const float* __restrict__ embW,
                            const float* __restrict__ embB,
                            float* __restrict__ cond_out)
{
    __shared__ float sl[NCC];
    __shared__ float se[EE];
    __shared__ float sc[NCC*EE];
    int b = blockIdx.x;
    int tid = threadIdx.x;
    if (tid < NCC) sl[tid] = label[b*NCC + tid];
    else if (tid >= 32 && tid < 32+EE) se[tid-32] = cemb[b*EE + (tid-32)];
    __syncthreads();
    for (int i = tid; i < NCC*EE; i += 256) sc[i] = sl[i>>6]*se[i&63];
    __syncthreads();
    for (int j = tid; j < HH; j += 256){
        const float* w = embW + (size_t)j*INWW + FF;
        float acc = embB[j];
        #pragma unroll 8
        for (int i = 0; i < NCC*EE; ++i) acc += sc[i]*w[i];
        cond_out[b*HH + j] = acc;
    }
}

// Mf[j][k] = sum_f embW[j][f]*outW[f][k]   (fp16 out)
__global__ void mf_kernel(const float* __restrict__ embW,
                          const float* __restrict__ outW,
                          _Float16* __restrict__ Mf)
{
    int idx = blockIdx.x*256 + threadIdx.x;   // 512*512
    int j = idx >> 9, k = idx & 511;
    const float* ew = embW + (size_t)j*INWW;
    float acc = 0.f;
    #pragma unroll 8
    for (int f = 0; f < FF; ++f) acc += ew[f] * outW[f*512 + k];
    Mf[idx] = (_Float16)acc;
}

// biasC[4][2048], w712[512], constj[512], outWf[80][512] (fp16, zero-padded)
__global__ void prep_kernel(const float* __restrict__ encbih, const float* __restrict__ encbhh,
                            const float* __restrict__ decbih, const float* __restrict__ decbhh,
                            const float* __restrict__ embW, const float* __restrict__ outW,
                            const float* __restrict__ outB,
                            float* __restrict__ biasC, float* __restrict__ w712,
                            float* __restrict__ constj, _Float16* __restrict__ outWf)
{
    int i = blockIdx.x*256 + threadIdx.x;
    if (i < 8192){
        int l = i >> 11, g = i & 2047;
        biasC[i] = (l < 2) ? encbih[l*GG+g] + encbhh[l*GG+g]
                           : decbih[(l-2)*GG+g] + decbhh[(l-2)*GG+g];
    } else if (i < 8704){
        int j = i - 8192;
        w712[j] = embW[(size_t)j*INWW + (INWW-1)];
    } else if (i < 9216){
        int j = i - 8704;
        float acc = 0.f;
        #pragma unroll 8
        for (int f = 0; f < FF; ++f) acc += embW[(size_t)j*INWW + f] * outB[f];
        constj[j] = acc;
    } else if (i < 9216 + 80*512){
        int ii = i - 9216;
        int f = ii >> 9, k = ii & 511;
        outWf[ii] = (f < FF) ? (_Float16)outW[f*512 + k] : (_Float16)0.f;
    }
}

// ---------------- persistent kernel (normal launch + flag group barriers) ----
// 256 blocks x 256 threads, 1 block/CU. rt = bid&7 (XCD-local group of 32 blocks),
// jt = bid>>3. Block owns rows rt*64..+63, h-cols jt*16..+15. Wave w = gate w.
__global__ __launch_bounds__(256, 1)
void persistent_kernel(const _Float16* __restrict__ wcat, const float* __restrict__ biasC,
                       const float* __restrict__ traj, const float* __restrict__ encW,
                       const float* __restrict__ encB, const float* __restrict__ prelu_a,
                       _Float16* __restrict__ xping, _Float16* __restrict__ h0p,
                       _Float16* __restrict__ h1p, _Float16* __restrict__ xdec,
                       const float* __restrict__ cond, const _Float16* __restrict__ Mf,
                       const float* __restrict__ w712, const float* __restrict__ constj,
                       const _Float16* __restrict__ outWf, const float* __restrict__ outB,
                       float* __restrict__ dout, unsigned* __restrict__ bar)
{
    __shared__ float gx[4][64][17];
    __shared__ float cst[2][64][17];

    const int tid = threadIdx.x;
    const int w    = tid >> 6;       // gate / row-subtile
    const int lane = tid & 63;
    const int m    = lane & 15;
    const int q    = lane >> 4;
    const int bid  = blockIdx.x;
    const int rt   = bid & 7;        // group id (XCD-local under %8 round-robin)
    const int jt   = bid >> 3;       // 0..31
    const int r0   = rt * 64;
    const int j0   = jt * 16;
    const float pa = prelu_a[0];
    unsigned* fl = bar + rt*32*32;   // 32 flags, 128B apart
    unsigned seq = 0;

    // Round-7 barrier, verbatim (fastest measured; no fences, no RMW, no
    // agent-release): __syncthreads() drains stores to the XCD L2, plain
    // volatile store of monotone seq to own flag, wave 0 polls via sc0 loads.
    auto gbar = [&](){
        ++seq;
        __syncthreads();
        if (tid == 0)
            *(volatile unsigned*)(fl + jt*32) = seq;
        if (tid < 64){
            long long t0 = clock64();
            for(;;){
                unsigned v = (tid < 32) ? *(volatile unsigned*)(fl + tid*32) : seq;
                if (__ballot((int)(seq - v) > 0) == 0ULL) break;
                __builtin_amdgcn_s_sleep(1);
                if (clock64() - t0 > 40000000LL) break;   // bail: wrong answer beats hang
            }
        }
        __syncthreads();
    };

    for (int i = tid; i < 2*64*17; i += 256) (&cst[0][0][0])[i] = 0.f;

    f16x8 WB0[32], WB1[32];
    auto load_wb = [&](const _Float16* base0, const _Float16* base1){
        const _Float16* p0 = base0 + ((size_t)(w*512 + j0 + m))*1024 + q*8;
        const _Float16* p1 = base1 + ((size_t)(w*512 + j0 + m))*1024 + q*8;
        #pragma unroll
        for (int kc = 0; kc < 32; ++kc){
            WB0[kc] = *(const f16x8*)(p0 + kc*32);
            WB1[kc] = *(const f16x8*)(p1 + kc*32);
        }
    };

    auto layer_step = [&](const f16x8* WB, float bb, const _Float16* A1, const _Float16* A2,
                          _Float16* dst, int cidx){
        f32x4 acc[4];
        #pragma unroll
        for (int rf = 0; rf < 4; ++rf){ acc[rf][0]=bb; acc[rf][1]=bb; acc[rf][2]=bb; acc[rf][3]=bb; }
        i32x4 s1 = make_srd(A1);
        i32x4 s2 = make_srd(A2);
        const int vb = (r0 + m)*1024 + q*16;     // bytes: row stride 512*2
        #pragma unroll
        for (int kc = 0; kc < 16; ++kc){
            #pragma unroll
            for (int rf = 0; rf < 4; ++rf){
                f16x8 av = ldA(s1, vb + rf*16*1024 + kc*64);
                acc[rf] = __builtin_amdgcn_mfma_f32_16x16x32_f16(av, WB[kc], acc[rf], 0,0,0);
            }
        }
        #pragma unroll
        for (int kc = 0; kc < 16; ++kc){
            #pragma unroll
            for (int rf = 0; rf < 4; ++rf){
                f16x8 av = ldA(s2, vb + rf*16*1024 + kc*64);
                acc[rf] = __builtin_amdgcn_mfma_f32_16x16x32_f16(av, WB[16+kc], acc[rf], 0,0,0);
            }
        }
        __syncthreads();
        #pragma unroll
        for (int rf = 0; rf < 4; ++rf)
            #pragma unroll
            for (int r = 0; r < 4; ++r)
                gx[w][rf*16 + q*4 + r][m] = acc[rf][r];
        __syncthreads();
        #pragma unroll
        for (int r = 0; r < 4; ++r){
            int row = w*16 + q*4 + r;
            float ig = sigmoidf_(gx[0][row][m]);
            float fg = sigmoidf_(gx[1][row][m]);
            float gv = tanhf(gx[2][row][m]);
            float og = sigmoidf_(gx[3][row][m]);
            float cp = cst[cidx][row][m];
            float cn = fg*cp + ig*gv;
            cst[cidx][row][m] = cn;
            dst[((size_t)(r0 + row))*512 + j0 + m] = (_Float16)(og*tanhf(cn));
        }
    };

    auto gen_x = [&](int t, _Float16* xd){
        #pragma unroll
        for (int e = 0; e < 4; ++e){
            int idx = e*256 + tid;
            int row = r0 + jt*2 + (idx >> 9);
            int col = idx & 511;
            const float* tr = traj + ((size_t)row*TTRAJ + t)*3;
            const float* wv = encW + col*3;
            float v = encB[col] + tr[0]*wv[0] + tr[1]*wv[1] + tr[2]*wv[2];
            xd[(size_t)row*512 + col] = (_Float16)(v >= 0.f ? v : pa*v);
        }
    };

    auto emb_step = [&](int d, const _Float16* h1prev){
        f32x4 acc = {0.f,0.f,0.f,0.f};
        if (d > 0){
            i32x4 sh = make_srd(h1prev);
            const int vb = (r0 + w*16 + m)*1024 + q*16;
            const _Float16* bp = Mf + ((size_t)(j0 + m))*512 + q*8;
            #pragma unroll
            for (int kc = 0; kc < 16; ++kc)
                acc = __builtin_amdgcn_mfma_f32_16x16x32_f16(
                    ldA(sh, vb + kc*64), *(const f16x8*)(bp + kc*32), acc, 0,0,0);
        }
        const int col = j0 + m;
        const float ts = (float)(d+1) * (1.0f/120.0f);
        const float add = ts * w712[col] + ((d > 0) ? constj[col] : 0.f);
        #pragma unroll
        for (int r = 0; r < 4; ++r){
            int row = r0 + w*16 + q*4 + r;
            float v = acc[r] + cond[(size_t)row*512 + col] + add;
            xdec[(size_t)row*512 + col] = (_Float16)(v >= 0.f ? v : pa*v);
        }
    };

    // out tiles stay inside group rows: block jt<20, wave 0: tile (jt/5, jt%5)
    auto out_step = [&](int dprev, const _Float16* h1v){
        if (jt >= 20 || w != 0) return;
        int b0 = r0 + (jt/5)*16;
        int f0 = (jt%5)*16;
        f32x4 acc = {0.f,0.f,0.f,0.f};
        i32x4 sh = make_srd(h1v);
        const int vb = (b0 + m)*1024 + q*16;
        const _Float16* bp = outWf + ((size_t)(f0 + m))*512 + q*8;
        #pragma unroll
        for (int kc = 0; kc < 16; ++kc)
            acc = __builtin_amdgcn_mfma_f32_16x16x32_f16(
                ldA(sh, vb + kc*64), *(const f16x8*)(bp + kc*32), acc, 0,0,0);
        int f = f0 + m;
        if (f < FF){
            float ob = outB[f];
            #pragma unroll
            for (int r = 0; r < 4; ++r){
                int b = b0 + q*4 + r;
                dout[((size_t)b*TOUT + dprev)*FF + f] = acc[r] + ob;
            }
        }
    };

    // ---- load encoder weights into registers ----
    load_wb(wcat + 0*WSZE, wcat + 1*WSZE);
    float bb0 = biasC[0*GG + w*512 + j0 + m];
    float bb1 = biasC[1*GG + w*512 + j0 + m];
    __syncthreads();

    gen_x(0, xping);
    gbar();

    // ---- encoder: segment t pairs L1(t-1) with L0(t): 1 barrier per step ----
    for (int t = 0; t <= 120; ++t){
        int cur = t & 1, prv = cur ^ 1;
        if (t >= 1)
            layer_step(WB1, bb1, h0p + (size_t)prv*BH, h1p + (size_t)cur*BH, h1p + (size_t)prv*BH, 1);
        if (t < 120){
            layer_step(WB0, bb0, xping + (size_t)cur*BH, h0p + (size_t)prv*BH, h0p + (size_t)cur*BH, 0);
            if (t + 1 < 120) gen_x(t + 1, xping + (size_t)prv*BH);
        }
        gbar();
    }

    // ---- decoder: reload registers with decoder weights ----
    load_wb(wcat + 2*WSZE, wcat + 3*WSZE);
    bb0 = biasC[2*GG + w*512 + j0 + m];
    bb1 = biasC[3*GG + w*512 + j0 + m];

    for (int d = 0; d < 120; ++d){
        int t = 120 + d; int cur = t & 1, prv = cur ^ 1;
        emb_step(d, h1p + (size_t)prv*BH);
        if (d > 0) out_step(d - 1, h1p + (size_t)prv*BH);
        gbar();
        layer_step(WB0, bb0, xdec, h0p + (size_t)prv*BH, h0p + (size_t)cur*BH, 0);
        gbar();
        layer_step(WB1, bb1, h0p + (size_t)cur*BH, h1p + (size_t)prv*BH, h1p + (size_t)cur*BH, 1);
        gbar();
    }
    out_step(119, h1p + (size_t)1*BH);
}

extern "C" void kernel_launch(void* const* d_in, const int* in_sizes, int n_in,
                              void* d_out, int out_size, void* d_ws, size_t ws_size,
                              hipStream_t stream)
{
    (void)in_sizes; (void)n_in; (void)out_size; (void)ws_size;
    const float* label   = (const float*)d_in[1];
    const float* cemb    = (const float*)d_in[2];
    const float* traj    = (const float*)d_in[3];
    const float* encW    = (const float*)d_in[4];
    const float* encB    = (const float*)d_in[5];
    const float* prelu_a = (const float*)d_in[6];
    const float* embW    = (const float*)d_in[7];
    const float* embB    = (const float*)d_in[8];
    const float* outW    = (const float*)d_in[9];
    const float* outB    = (const float*)d_in[10];
    const float* encWih  = (const float*)d_in[11];
    const float* encWhh  = (const float*)d_in[12];
    const float* encbih  = (const float*)d_in[13];
    const float* encbhh  = (const float*)d_in[14];
    const float* decWih  = (const float*)d_in[15];
    const float* decWhh  = (const float*)d_in[16];
    const float* decbih  = (const float*)d_in[17];
    const float* decbhh  = (const float*)d_in[18];
    float* out = (float*)d_out;

    char* ws = (char*)d_ws;
    size_t off = 0;
    auto alloc = [&](size_t bytes)->char*{
        char* p = ws + off; off = (off + bytes + 255) & ~(size_t)255; return p;
    };
    _Float16* wcat  = (_Float16*)alloc(4*WSZE*2);
    _Float16* xping = (_Float16*)alloc(2*BH*2);
    _Float16* h0p   = (_Float16*)alloc(2*BH*2);
    _Float16* h1p   = (_Float16*)alloc(2*BH*2);
    _Float16* xdec  = (_Float16*)alloc(BH*2);
    float*    cond  = (float*)   alloc(BH*4);
    _Float16* Mf    = (_Float16*)alloc(512*512*2);
    _Float16* outWf = (_Float16*)alloc(80*512*2);
    float*    biasC = (float*)   alloc(4*GG*4);
    float*    w712  = (float*)   alloc(512*4);
    float*    constj= (float*)   alloc(512*4);
    unsigned* bar   = (unsigned*)alloc(8*32*32*4);   // 8 groups x 32 flags x 128B

    // zero h0p + h1p (contiguous 2MB) and barrier flags
    hipMemsetAsync(h0p, 0, 4*BH*2, stream);
    hipMemsetAsync(bar, 0, 8*32*32*4, stream);

    conv_wcat_kernel<<<2048, 256, 0, stream>>>(encWih,                 encWhh,                 wcat + 0*WSZE);
    conv_wcat_kernel<<<2048, 256, 0, stream>>>(encWih + (size_t)GG*HH, encWhh + (size_t)GG*HH, wcat + 1*WSZE);
    conv_wcat_kernel<<<2048, 256, 0, stream>>>(decWih,                 decWhh,                 wcat + 2*WSZE);
    conv_wcat_kernel<<<2048, 256, 0, stream>>>(decWih + (size_t)GG*HH, decWhh + (size_t)GG*HH, wcat + 3*WSZE);
    cond_kernel<<<BB, 256, 0, stream>>>(label, cemb, embW, embB, cond);
    mf_kernel<<<1024, 256, 0, stream>>>(embW, outW, Mf);
    prep_kernel<<<197, 256, 0, stream>>>(encbih, encbhh, decbih, decbhh, embW, outW, outB,
                                         biasC, w712, constj, outWf);

    persistent_kernel<<<256, 256, 0, stream>>>(
        wcat, biasC, traj, encW, encB, prelu_a, xping, h0p, h1p, xdec,
        cond, Mf, w712, constj, outWf, outB, out, bar);
}